// Round 7
// baseline (307.652 us; speedup 1.0000x reference)
//
#include <hip/hip_runtime.h>
#include <hip/hip_bf16.h>
#include <math.h>

#define H_DIM 4096
#define N_EXP 64
#define N_TOK 16384
#define BM    64
#define KB    64
#define NCHUNK (H_DIM / KB)   // 64
#define MARGIN 1e-3f

typedef __attribute__((ext_vector_type(8))) short short8v;
typedef __attribute__((ext_vector_type(4))) float float4v;

__device__ __forceinline__ unsigned short bf16_rn(float f) {
    unsigned u = __builtin_bit_cast(unsigned, f);
    u += 0x7FFFu + ((u >> 16) & 1u);
    return (unsigned short)(u >> 16);
}
__device__ __forceinline__ float bf16_hi_f32(unsigned u) {
    return __builtin_bit_cast(float, u & 0xFFFF0000u);
}
__device__ __forceinline__ void gload_lds16(const void* g, void* l) {
    __builtin_amdgcn_global_load_lds(
        (const __attribute__((address_space(1))) unsigned int*)g,
        (__attribute__((address_space(3))) unsigned int*)l, 16, 0, 0);
}

// ---- W split: w = wh(trunc) + wm(rn) + wl(rn); zero the fixup counter ----
__global__ __launch_bounds__(256)
void wconvert_kernel(const float* __restrict__ W,
                     unsigned short* __restrict__ wh,
                     unsigned short* __restrict__ wm,
                     unsigned short* __restrict__ wl,
                     int* __restrict__ counter) {
    int i = blockIdx.x * 256 + threadIdx.x;
    if (i == 0) *counter = 0;
    float w = W[i];
    unsigned u = __builtin_bit_cast(unsigned, w);
    wh[i] = (unsigned short)(u >> 16);
    float r1 = w - bf16_hi_f32(u);
    unsigned short m = bf16_rn(r1);
    wm[i] = m;
    float r2 = r1 - bf16_hi_f32((unsigned)m << 16);
    wl[i] = bf16_rn(r2);
}

// ---- logits: 6-term split-bf16 MFMA; x via LDS, W via register prefetch ----
__global__ __launch_bounds__(512, 2)
void router_mfma_kernel(const float* __restrict__ x,
                        const unsigned short* __restrict__ wh,
                        const unsigned short* __restrict__ wm,
                        const unsigned short* __restrict__ wl,
                        const float* __restrict__ bias,
                        float* __restrict__ logits) {
    __shared__ float4 xlds[2][1024];   // 2 x 16 KB

    const int tid  = threadIdx.x;
    const int lane = tid & 63;
    const int wid  = __builtin_amdgcn_readfirstlane(tid >> 6);
    const int tok0 = blockIdx.x * BM;

    const int q    = lane >> 4;
    const int e15  = lane & 15;
    const int mt   = wid & 3;            // m-tile (16 rows)
    const int nh   = wid >> 2;           // n-half (32 experts)
    const int arow = mt * 16 + e15;
    const int e0   = nh * 32 + e15;
    const int e1   = nh * 32 + 16 + e15;

    // per-lane W base pointers (bytes): [term][e0/e1]; +128 B per chunk
    const unsigned short* wb0[3] = {wh, wm, wl};
    const char* wbase[3][2];
#pragma unroll
    for (int s = 0; s < 3; ++s) {
        wbase[s][0] = (const char*)(wb0[s] + (size_t)e0 * H_DIM + q * 8);
        wbase[s][1] = (const char*)(wb0[s] + (size_t)e1 * H_DIM + q * 8);
    }

    float4v acc0 = {0.f, 0.f, 0.f, 0.f};
    float4v acc1 = {0.f, 0.f, 0.f, 0.f};

    auto issue_x = [&](int cb, int kc) {
#pragma unroll
        for (int i = 0; i < 2; ++i) {
            int uph = i * 512 + tid;
            int row = uph >> 4, up = uph & 15;
            int u4  = up ^ (row & 15);                 // pre-swizzled source
            const float* src = x + (size_t)(tok0 + row) * H_DIM + kc + u4 * 4;
            void* dst = (char*)&xlds[cb][0] + (size_t)(i * 512 + wid * 64) * 16;
            gload_lds16(src, dst);
        }
    };
    auto issue_w = [&](short8v (&set)[2][3][2], int c) {
        const int boff = c * (KB * 2);                 // 128 B per chunk
#pragma unroll
        for (int t = 0; t < 2; ++t)
#pragma unroll
            for (int s = 0; s < 3; ++s)
#pragma unroll
                for (int n = 0; n < 2; ++n)
                    set[t][s][n] = *(const short8v*)(wbase[s][n] + boff + t * 64);
    };
    auto compute = [&](int cb, short8v (&set)[2][3][2]) {
        const char* bufc = (const char*)&xlds[cb][0];
#pragma unroll
        for (int t = 0; t < 2; ++t) {
            float f[8];
#pragma unroll
            for (int h = 0; h < 2; ++h) {
                int u4 = (t * 8 + q * 2 + h) ^ e15;
                float4 a = *(const float4*)(bufc + (size_t)(arow * 16 + u4) * 16);
                f[h * 4 + 0] = a.x; f[h * 4 + 1] = a.y;
                f[h * 4 + 2] = a.z; f[h * 4 + 3] = a.w;
            }
            short8v ah, am, al;
#pragma unroll
            for (int j = 0; j < 8; ++j) {
                unsigned u = __builtin_bit_cast(unsigned, f[j]);
                ah[j] = (short)(u >> 16);
                float r1 = f[j] - bf16_hi_f32(u);
                unsigned u1 = __builtin_bit_cast(unsigned, r1);
                am[j] = (short)(u1 >> 16);
                float r2 = r1 - bf16_hi_f32(u1);
                al[j] = (short)bf16_rn(r2);
            }
            acc0 = __builtin_amdgcn_mfma_f32_16x16x32_bf16(ah, set[t][0][0], acc0, 0, 0, 0);
            acc1 = __builtin_amdgcn_mfma_f32_16x16x32_bf16(ah, set[t][0][1], acc1, 0, 0, 0);
            acc0 = __builtin_amdgcn_mfma_f32_16x16x32_bf16(am, set[t][0][0], acc0, 0, 0, 0);
            acc1 = __builtin_amdgcn_mfma_f32_16x16x32_bf16(am, set[t][0][1], acc1, 0, 0, 0);
            acc0 = __builtin_amdgcn_mfma_f32_16x16x32_bf16(ah, set[t][1][0], acc0, 0, 0, 0);
            acc1 = __builtin_amdgcn_mfma_f32_16x16x32_bf16(ah, set[t][1][1], acc1, 0, 0, 0);
            acc0 = __builtin_amdgcn_mfma_f32_16x16x32_bf16(am, set[t][1][0], acc0, 0, 0, 0);
            acc1 = __builtin_amdgcn_mfma_f32_16x16x32_bf16(am, set[t][1][1], acc1, 0, 0, 0);
            acc0 = __builtin_amdgcn_mfma_f32_16x16x32_bf16(al, set[t][0][0], acc0, 0, 0, 0);
            acc1 = __builtin_amdgcn_mfma_f32_16x16x32_bf16(al, set[t][0][1], acc1, 0, 0, 0);
            acc0 = __builtin_amdgcn_mfma_f32_16x16x32_bf16(ah, set[t][2][0], acc0, 0, 0, 0);
            acc1 = __builtin_amdgcn_mfma_f32_16x16x32_bf16(ah, set[t][2][1], acc1, 0, 0, 0);
        }
    };

    short8v wA[2][3][2], wB[2][3][2];
    issue_x(0, 0);
    issue_w(wA, 0);
    for (int cc = 0; cc < NCHUNK; cc += 2) {
        __builtin_amdgcn_s_barrier();                  // buf1 free (prev compute done)
        issue_x(1, (cc + 1) * KB);
        issue_w(wB, cc + 1);
        asm volatile("s_waitcnt vmcnt(14)" ::: "memory");   // chunk cc landed
        __builtin_amdgcn_s_barrier();
        compute(0, wA);
        __builtin_amdgcn_s_barrier();                  // buf0 free
        if (cc + 2 < NCHUNK) {
            issue_x(0, (cc + 2) * KB);
            issue_w(wA, cc + 2);
            asm volatile("s_waitcnt vmcnt(14)" ::: "memory");
        } else {
            asm volatile("s_waitcnt vmcnt(0)" ::: "memory");
        }
        __builtin_amdgcn_s_barrier();
        compute(1, wB);
    }

    float bv0 = bias[e0], bv1 = bias[e1];
#pragma unroll
    for (int r = 0; r < 4; ++r) {
        int token = tok0 + mt * 16 + q * 4 + r;        // C: row=(lane>>4)*4+r, col=lane&15
        logits[(size_t)token * N_EXP + e0] = acc0[r] + bv0;
        logits[(size_t)token * N_EXP + e1] = acc1[r] + bv1;
    }
}

// ---- fallback exact-f32 GEMM ----
__global__ __launch_bounds__(256)
void router_logits_f32(const float* __restrict__ x,
                       const float* __restrict__ W,
                       const float* __restrict__ bias,
                       float* __restrict__ logits) {
    __shared__ float4 wlds[32 * 64];
    __shared__ float4 xlds[32][32];
    const int tid = threadIdx.x;
    const int lane = tid & 63;
    const int wid = __builtin_amdgcn_readfirstlane(tid >> 6);
    const int tok0b = blockIdx.x * 32;
    const int trow0 = wid * 8;
    float acc[8];
#pragma unroll
    for (int t = 0; t < 8; ++t) acc[t] = 0.0f;
    for (int kc = 0; kc < H_DIM; kc += 128) {
        __syncthreads();
#pragma unroll
        for (int i = 0; i < 8; ++i) {
            int idx = tid + i * 256;
            int se = idx >> 5, sj = idx & 31;
            float4 v = *(const float4*)(W + (size_t)se * H_DIM + kc + sj * 4);
            wlds[sj * 64 + (se ^ (sj & 7))] = v;
        }
#pragma unroll
        for (int i = 0; i < 4; ++i) {
            int idx = tid + i * 256;
            int row = idx >> 5, col = idx & 31;
            xlds[row][col] = *(const float4*)(x + (size_t)(tok0b + row) * H_DIM + kc + col * 4);
        }
        __syncthreads();
#pragma unroll 4
        for (int jg = 0; jg < 32; ++jg) {
            float4 w = wlds[jg * 64 + (lane ^ (jg & 7))];
#pragma unroll
            for (int t = 0; t < 8; ++t) {
                float4 xv = xlds[trow0 + t][jg];
                acc[t] = fmaf(w.x, xv.x, acc[t]);
                acc[t] = fmaf(w.y, xv.y, acc[t]);
                acc[t] = fmaf(w.z, xv.z, acc[t]);
                acc[t] = fmaf(w.w, xv.w, acc[t]);
            }
        }
    }
    float bv = bias[lane];
#pragma unroll
    for (int t = 0; t < 8; ++t)
        logits[(size_t)(tok0b + trow0 + t) * N_EXP + lane] = acc[t] + bv;
}

// ---- wave-parallel softmax + top-2 (+ near-tie flag) ----
template <int FIX>
__global__ __launch_bounds__(256)
void topk_kernel(const float* __restrict__ logits,
                 float* __restrict__ wout,
                 float* __restrict__ iout,
                 int* __restrict__ counter,
                 int* __restrict__ list) {
    const int lane = threadIdx.x & 63;
    const int wid  = threadIdx.x >> 6;
    const int wg   = blockIdx.x * 4 + wid;           // global wave id
#pragma unroll
    for (int it = 0; it < 4; ++it) {
        const int n = wg * 4 + it;
        float l = logits[(size_t)n * N_EXP + lane];

        // argmax (lowest index wins ties)
        float v1 = l; int i1 = lane;
#pragma unroll
        for (int off = 32; off >= 1; off >>= 1) {
            float ov = __shfl_xor(v1, off);
            int   oi = __shfl_xor(i1, off);
            if (ov > v1 || (ov == v1 && oi < i1)) { v1 = ov; i1 = oi; }
        }
        float l2 = (lane == i1) ? -INFINITY : l;
        float v2 = l2; int i2 = lane;
#pragma unroll
        for (int off = 32; off >= 1; off >>= 1) {
            float ov = __shfl_xor(v2, off);
            int   oi = __shfl_xor(i2, off);
            if (ov > v2 || (ov == v2 && oi < i2)) { v2 = ov; i2 = oi; }
        }
        float v3 = -INFINITY;
        if (FIX) {
            float l3 = (lane == i1 || lane == i2) ? -INFINITY : l;
            v3 = l3;
#pragma unroll
            for (int off = 32; off >= 1; off >>= 1)
                v3 = fmaxf(v3, __shfl_xor(v3, off));
        }
        float s = expf(l - v1);
        float Z = s;
#pragma unroll
        for (int off = 32; off >= 1; off >>= 1) Z += __shfl_xor(Z, off);

        if (lane == 0) {
            float p1 = 1.0f / Z;
            float p2 = expf(v2 - v1) / Z;
            float t  = expf(p2 - p1);
            wout[2 * n + 0] = 1.0f / (1.0f + t);
            wout[2 * n + 1] = t / (1.0f + t);
            iout[2 * n + 0] = (float)i1;
            iout[2 * n + 1] = (float)i2;
            if (FIX) {
                if ((v1 - v2 < MARGIN) || (v2 - v3 < MARGIN)) {
                    int sidx = atomicAdd(counter, 1);
                    list[sidx] = n;
                }
            }
        }
    }
}

// ---- exact-f32 recompute of flagged tokens ----
__global__ __launch_bounds__(256)
void fixup_kernel(const float* __restrict__ x,
                  const float* __restrict__ W,
                  const float* __restrict__ bias,
                  float* __restrict__ wout,
                  float* __restrict__ iout,
                  const int* __restrict__ counter,
                  const int* __restrict__ list) {
    __shared__ float plds[4][64];
    __shared__ float llds[64];
    int cnt = counter[0];
    if (cnt > N_TOK) cnt = N_TOK;
    const int e = threadIdx.x & 63;
    const int s = threadIdx.x >> 6;
    for (int it = blockIdx.x; it < cnt; it += 128) {
        int n = list[it];
        const float4* xr = (const float4*)(x + (size_t)n * H_DIM) + s * 256;
        const float4* wr = (const float4*)(W + (size_t)e * H_DIM) + s * 256;
        float p = 0.f;
#pragma unroll 8
        for (int j = 0; j < 256; ++j) {
            float4 a = xr[j], w = wr[j];
            p = fmaf(a.x, w.x, p); p = fmaf(a.y, w.y, p);
            p = fmaf(a.z, w.z, p); p = fmaf(a.w, w.w, p);
        }
        plds[s][e] = p;
        __syncthreads();
        if (threadIdx.x < 64)
            llds[e] = ((plds[0][e] + plds[1][e]) + (plds[2][e] + plds[3][e])) + bias[e];
        __syncthreads();
        if (threadIdx.x == 0) {
            float v1 = -INFINITY, v2 = -INFINITY;
            int i1 = 0, i2 = 0;
            for (int i = 0; i < 64; ++i) {
                float li = llds[i];
                if (li > v1)      { v2 = v1; i2 = i1; v1 = li; i1 = i; }
                else if (li > v2) { v2 = li; i2 = i; }
            }
            float Z = 0.0f;
            for (int i = 0; i < 64; ++i) Z += expf(llds[i] - v1);
            float p1 = 1.0f / Z;
            float p2 = expf(v2 - v1) / Z;
            float t  = expf(p2 - p1);
            wout[2 * n + 0] = 1.0f / (1.0f + t);
            wout[2 * n + 1] = t / (1.0f + t);
            iout[2 * n + 0] = (float)i1;
            iout[2 * n + 1] = (float)i2;
        }
        __syncthreads();
    }
}

// ---- expert mask [E][K][N] ----
__global__ __launch_bounds__(256)
void mask_kernel(const float* __restrict__ iout,
                 float* __restrict__ mask) {
    int gid = blockIdx.x * 256 + threadIdx.x;
    int n   = gid & (N_TOK - 1);
    int ek  = gid >> 14;
    float idxf = iout[(size_t)n * 2 + (ek & 1)];
    mask[gid] = (idxf == (float)(ek >> 1)) ? 1.0f : 0.0f;
}

extern "C" void kernel_launch(void* const* d_in, const int* in_sizes, int n_in,
                              void* d_out, int out_size, void* d_ws, size_t ws_size,
                              hipStream_t stream) {
    const float* x  = (const float*)d_in[0];
    const float* W  = (const float*)d_in[1];
    const float* b  = (const float*)d_in[2];

    float* out    = (float*)d_out;
    float* logits = out;
    float* wout   = logits + (size_t)N_TOK * 64;
    float* iout   = wout   + (size_t)N_TOK * 2;
    float* mask   = iout   + (size_t)N_TOK * 2;

    const size_t wsplit = (size_t)N_EXP * H_DIM;                       // 262144
    const size_t need   = 3 * wsplit * sizeof(unsigned short) + 4 + (size_t)N_TOK * 4;
    if (ws_size >= need) {
        unsigned short* wh = (unsigned short*)d_ws;
        unsigned short* wm = wh + wsplit;
        unsigned short* wl = wm + wsplit;
        int* counter = (int*)((char*)d_ws + 3 * wsplit * sizeof(unsigned short));
        int* list    = counter + 1;
        wconvert_kernel<<<(int)(wsplit / 256), 256, 0, stream>>>(W, wh, wm, wl, counter);
        router_mfma_kernel<<<N_TOK / BM, 512, 0, stream>>>(x, wh, wm, wl, b, logits);
        topk_kernel<1><<<N_TOK / 16, 256, 0, stream>>>(logits, wout, iout, counter, list);
        fixup_kernel<<<128, 256, 0, stream>>>(x, W, b, wout, iout, counter, list);
    } else {
        router_logits_f32<<<N_TOK / 32, 256, 0, stream>>>(x, W, b, logits);
        topk_kernel<0><<<N_TOK / 16, 256, 0, stream>>>(logits, wout, iout, nullptr, nullptr);
    }
    mask_kernel<<<(N_EXP * 2 * N_TOK) / 256, 256, 0, stream>>>(iout, mask);
}

// Round 8
// 262.886 us; speedup vs baseline: 1.1703x; 1.1703x over previous
//
#include <hip/hip_runtime.h>
#include <hip/hip_bf16.h>
#include <math.h>

#define H_DIM 4096
#define N_EXP 64
#define N_TOK 16384
#define BM    16
#define KB    64
#define NCHUNK (H_DIM / KB)   // 64
#define MARGIN 1e-3f

typedef __attribute__((ext_vector_type(8))) short short8v;
typedef __attribute__((ext_vector_type(4))) float float4v;

__device__ __forceinline__ unsigned short bf16_rn(float f) {
    unsigned u = __builtin_bit_cast(unsigned, f);
    u += 0x7FFFu + ((u >> 16) & 1u);
    return (unsigned short)(u >> 16);
}
__device__ __forceinline__ float bf16_hi_f32(unsigned u) {
    return __builtin_bit_cast(float, u & 0xFFFF0000u);
}
__device__ __forceinline__ void gload_lds16(const void* g, void* l) {
    __builtin_amdgcn_global_load_lds(
        (const __attribute__((address_space(1))) unsigned int*)g,
        (__attribute__((address_space(3))) unsigned int*)l, 16, 0, 0);
}

// ---- W split: w = wh(trunc) + wm(rn) + wl(rn); zero the fixup counter ----
__global__ __launch_bounds__(256)
void wconvert_kernel(const float* __restrict__ W,
                     unsigned short* __restrict__ wh,
                     unsigned short* __restrict__ wm,
                     unsigned short* __restrict__ wl,
                     int* __restrict__ counter) {
    int i = blockIdx.x * 256 + threadIdx.x;
    if (i == 0) *counter = 0;
    float w = W[i];
    unsigned u = __builtin_bit_cast(unsigned, w);
    wh[i] = (unsigned short)(u >> 16);
    float r1 = w - bf16_hi_f32(u);
    unsigned short m = bf16_rn(r1);
    wm[i] = m;
    float r2 = r1 - bf16_hi_f32((unsigned)m << 16);
    wl[i] = bf16_rn(r2);
}

// ---- logits: 6-term split-bf16 MFMA. BM=16, 4 blocks/CU, W loaded at use ----
__global__ __launch_bounds__(256, 4)
void router_mfma_kernel(const float* __restrict__ x,
                        const unsigned short* __restrict__ wh,
                        const unsigned short* __restrict__ wm,
                        const unsigned short* __restrict__ wl,
                        const float* __restrict__ bias,
                        float* __restrict__ logits) {
    __shared__ float4 xlds[2][256];   // 2 x 4 KB

    const int tid  = threadIdx.x;
    const int lane = tid & 63;
    const int wid  = __builtin_amdgcn_readfirstlane(tid >> 6);
    const int tok0 = blockIdx.x * BM;

    const int q    = lane >> 4;       // 0..3
    const int e15  = lane & 15;
    const int erow = wid * 16 + e15;  // this wave's expert for B frags
    const int arow = e15;             // token row for A frags (BM=16)

    // byte base of this wave's W rows at k-offset q*8 shorts (=16B)
    const char* wbh = (const char*)(wh + (size_t)erow * H_DIM + q * 8);
    const char* wbm = (const char*)(wm + (size_t)erow * H_DIM + q * 8);
    const char* wbl = (const char*)(wl + (size_t)erow * H_DIM + q * 8);

    float4v acc = {0.f, 0.f, 0.f, 0.f};

    auto issue_x = [&](int cb, int kc) {
        // 256 units: row = tid>>4, unit u = tid&15, source pre-swizzled u^row
        int row = tid >> 4, u = tid & 15;
        int gu  = u ^ row;
        const float* src = x + (size_t)(tok0 + row) * H_DIM + kc + gu * 4;
        void* dst = (char*)&xlds[cb][0] + (size_t)(wid * 64) * 16;  // wave-uniform
        gload_lds16(src, dst);
    };

    auto compute = [&](int cb, int kc) {
        const char* bufc = (const char*)&xlds[cb][0];
        const int boff = kc * 2;                    // bytes per k (2B shorts)
#pragma unroll
        for (int t = 0; t < 2; ++t) {
            // W fragments first (independent L2 loads)
            short8v bh = *(const short8v*)(wbh + boff + t * 64);
            short8v bm = *(const short8v*)(wbm + boff + t * 64);
            short8v bl = *(const short8v*)(wbl + boff + t * 64);
            // A fragment: 8 consecutive k f32 from LDS (swizzled)
            float f[8];
#pragma unroll
            for (int h = 0; h < 2; ++h) {
                int u = (t * 8 + q * 2 + h) ^ arow;
                float4 a = *(const float4*)(bufc + (size_t)(arow * 16 + u) * 16);
                f[h * 4 + 0] = a.x; f[h * 4 + 1] = a.y;
                f[h * 4 + 2] = a.z; f[h * 4 + 3] = a.w;
            }
            short8v ah, am, al;
#pragma unroll
            for (int j = 0; j < 8; ++j) {
                unsigned u = __builtin_bit_cast(unsigned, f[j]);
                ah[j] = (short)(u >> 16);
                float r1 = f[j] - bf16_hi_f32(u);
                unsigned u1 = __builtin_bit_cast(unsigned, r1);
                am[j] = (short)(u1 >> 16);
                float r2 = r1 - bf16_hi_f32(u1);
                al[j] = (short)bf16_rn(r2);
            }
            acc = __builtin_amdgcn_mfma_f32_16x16x32_bf16(ah, bh, acc, 0, 0, 0);
            acc = __builtin_amdgcn_mfma_f32_16x16x32_bf16(am, bh, acc, 0, 0, 0);
            acc = __builtin_amdgcn_mfma_f32_16x16x32_bf16(ah, bm, acc, 0, 0, 0);
            acc = __builtin_amdgcn_mfma_f32_16x16x32_bf16(am, bm, acc, 0, 0, 0);
            acc = __builtin_amdgcn_mfma_f32_16x16x32_bf16(al, bh, acc, 0, 0, 0);
            acc = __builtin_amdgcn_mfma_f32_16x16x32_bf16(ah, bl, acc, 0, 0, 0);
        }
    };

    issue_x(0, 0);
    for (int c = 0; c < NCHUNK; ++c) {
        __builtin_amdgcn_s_barrier();               // prev compute done, buf free
        if (c + 1 < NCHUNK) {
            issue_x((c + 1) & 1, (c + 1) * KB);
            asm volatile("s_waitcnt vmcnt(1)" ::: "memory");  // chunk c landed
        } else {
            asm volatile("s_waitcnt vmcnt(0)" ::: "memory");
        }
        __builtin_amdgcn_s_barrier();               // all threads' chunk-c data in LDS
        compute(c & 1, c * KB);
    }

    float bv = bias[erow];
#pragma unroll
    for (int r = 0; r < 4; ++r) {
        int token = tok0 + q * 4 + r;               // C: row=(lane>>4)*4+r, col=lane&15
        logits[(size_t)token * N_EXP + erow] = acc[r] + bv;
    }
}

// ---- fallback exact-f32 GEMM ----
__global__ __launch_bounds__(256)
void router_logits_f32(const float* __restrict__ x,
                       const float* __restrict__ W,
                       const float* __restrict__ bias,
                       float* __restrict__ logits) {
    __shared__ float4 wlds[32 * 64];
    __shared__ float4 xlds[32][32];
    const int tid = threadIdx.x;
    const int lane = tid & 63;
    const int wid = __builtin_amdgcn_readfirstlane(tid >> 6);
    const int tok0b = blockIdx.x * 32;
    const int trow0 = wid * 8;
    float acc[8];
#pragma unroll
    for (int t = 0; t < 8; ++t) acc[t] = 0.0f;
    for (int kc = 0; kc < H_DIM; kc += 128) {
        __syncthreads();
#pragma unroll
        for (int i = 0; i < 8; ++i) {
            int idx = tid + i * 256;
            int se = idx >> 5, sj = idx & 31;
            float4 v = *(const float4*)(W + (size_t)se * H_DIM + kc + sj * 4);
            wlds[sj * 64 + (se ^ (sj & 7))] = v;
        }
#pragma unroll
        for (int i = 0; i < 4; ++i) {
            int idx = tid + i * 256;
            int row = idx >> 5, col = idx & 31;
            xlds[row][col] = *(const float4*)(x + (size_t)(tok0b + row) * H_DIM + kc + col * 4);
        }
        __syncthreads();
#pragma unroll 4
        for (int jg = 0; jg < 32; ++jg) {
            float4 w = wlds[jg * 64 + (lane ^ (jg & 7))];
#pragma unroll
            for (int t = 0; t < 8; ++t) {
                float4 xv = xlds[trow0 + t][jg];
                acc[t] = fmaf(w.x, xv.x, acc[t]);
                acc[t] = fmaf(w.y, xv.y, acc[t]);
                acc[t] = fmaf(w.z, xv.z, acc[t]);
                acc[t] = fmaf(w.w, xv.w, acc[t]);
            }
        }
    }
    float bv = bias[lane];
#pragma unroll
    for (int t = 0; t < 8; ++t)
        logits[(size_t)(tok0b + trow0 + t) * N_EXP + lane] = acc[t] + bv;
}

// ---- wave-parallel softmax + top-2 (+ near-tie flag) ----
template <int FIX>
__global__ __launch_bounds__(256)
void topk_kernel(const float* __restrict__ logits,
                 float* __restrict__ wout,
                 float* __restrict__ iout,
                 int* __restrict__ counter,
                 int* __restrict__ list) {
    const int lane = threadIdx.x & 63;
    const int wid  = threadIdx.x >> 6;
    const int wg   = blockIdx.x * 4 + wid;           // global wave id
#pragma unroll
    for (int it = 0; it < 4; ++it) {
        const int n = wg * 4 + it;
        float l = logits[(size_t)n * N_EXP + lane];

        // argmax (lowest index wins ties)
        float v1 = l; int i1 = lane;
#pragma unroll
        for (int off = 32; off >= 1; off >>= 1) {
            float ov = __shfl_xor(v1, off);
            int   oi = __shfl_xor(i1, off);
            if (ov > v1 || (ov == v1 && oi < i1)) { v1 = ov; i1 = oi; }
        }
        float l2 = (lane == i1) ? -INFINITY : l;
        float v2 = l2; int i2 = lane;
#pragma unroll
        for (int off = 32; off >= 1; off >>= 1) {
            float ov = __shfl_xor(v2, off);
            int   oi = __shfl_xor(i2, off);
            if (ov > v2 || (ov == v2 && oi < i2)) { v2 = ov; i2 = oi; }
        }
        float v3 = -INFINITY;
        if (FIX) {
            float l3 = (lane == i1 || lane == i2) ? -INFINITY : l;
            v3 = l3;
#pragma unroll
            for (int off = 32; off >= 1; off >>= 1)
                v3 = fmaxf(v3, __shfl_xor(v3, off));
        }
        float s = expf(l - v1);
        float Z = s;
#pragma unroll
        for (int off = 32; off >= 1; off >>= 1) Z += __shfl_xor(Z, off);

        if (lane == 0) {
            float p1 = 1.0f / Z;
            float p2 = expf(v2 - v1) / Z;
            float t  = expf(p2 - p1);
            wout[2 * n + 0] = 1.0f / (1.0f + t);
            wout[2 * n + 1] = t / (1.0f + t);
            iout[2 * n + 0] = (float)i1;
            iout[2 * n + 1] = (float)i2;
            if (FIX) {
                if ((v1 - v2 < MARGIN) || (v2 - v3 < MARGIN)) {
                    int sidx = atomicAdd(counter, 1);
                    list[sidx] = n;
                }
            }
        }
    }
}

// ---- exact-f32 recompute of flagged tokens ----
__global__ __launch_bounds__(256)
void fixup_kernel(const float* __restrict__ x,
                  const float* __restrict__ W,
                  const float* __restrict__ bias,
                  float* __restrict__ wout,
                  float* __restrict__ iout,
                  const int* __restrict__ counter,
                  const int* __restrict__ list) {
    __shared__ float plds[4][64];
    __shared__ float llds[64];
    int cnt = counter[0];
    if (cnt > N_TOK) cnt = N_TOK;
    const int e = threadIdx.x & 63;
    const int s = threadIdx.x >> 6;
    for (int it = blockIdx.x; it < cnt; it += 128) {
        int n = list[it];
        const float4* xr = (const float4*)(x + (size_t)n * H_DIM) + s * 256;
        const float4* wr = (const float4*)(W + (size_t)e * H_DIM) + s * 256;
        float p = 0.f;
#pragma unroll 8
        for (int j = 0; j < 256; ++j) {
            float4 a = xr[j], w = wr[j];
            p = fmaf(a.x, w.x, p); p = fmaf(a.y, w.y, p);
            p = fmaf(a.z, w.z, p); p = fmaf(a.w, w.w, p);
        }
        plds[s][e] = p;
        __syncthreads();
        if (threadIdx.x < 64)
            llds[e] = ((plds[0][e] + plds[1][e]) + (plds[2][e] + plds[3][e])) + bias[e];
        __syncthreads();
        if (threadIdx.x == 0) {
            float v1 = -INFINITY, v2 = -INFINITY;
            int i1 = 0, i2 = 0;
            for (int i = 0; i < 64; ++i) {
                float li = llds[i];
                if (li > v1)      { v2 = v1; i2 = i1; v1 = li; i1 = i; }
                else if (li > v2) { v2 = li; i2 = i; }
            }
            float Z = 0.0f;
            for (int i = 0; i < 64; ++i) Z += expf(llds[i] - v1);
            float p1 = 1.0f / Z;
            float p2 = expf(v2 - v1) / Z;
            float t  = expf(p2 - p1);
            wout[2 * n + 0] = 1.0f / (1.0f + t);
            wout[2 * n + 1] = t / (1.0f + t);
            iout[2 * n + 0] = (float)i1;
            iout[2 * n + 1] = (float)i2;
        }
        __syncthreads();
    }
}

// ---- expert mask [E][K][N] ----
__global__ __launch_bounds__(256)
void mask_kernel(const float* __restrict__ iout,
                 float* __restrict__ mask) {
    int gid = blockIdx.x * 256 + threadIdx.x;
    int n   = gid & (N_TOK - 1);
    int ek  = gid >> 14;
    float idxf = iout[(size_t)n * 2 + (ek & 1)];
    mask[gid] = (idxf == (float)(ek >> 1)) ? 1.0f : 0.0f;
}

extern "C" void kernel_launch(void* const* d_in, const int* in_sizes, int n_in,
                              void* d_out, int out_size, void* d_ws, size_t ws_size,
                              hipStream_t stream) {
    const float* x  = (const float*)d_in[0];
    const float* W  = (const float*)d_in[1];
    const float* b  = (const float*)d_in[2];

    float* out    = (float*)d_out;
    float* logits = out;
    float* wout   = logits + (size_t)N_TOK * 64;
    float* iout   = wout   + (size_t)N_TOK * 2;
    float* mask   = iout   + (size_t)N_TOK * 2;

    const size_t wsplit = (size_t)N_EXP * H_DIM;                       // 262144
    const size_t need   = 3 * wsplit * sizeof(unsigned short) + 4 + (size_t)N_TOK * 4;
    if (ws_size >= need) {
        unsigned short* wh = (unsigned short*)d_ws;
        unsigned short* wm = wh + wsplit;
        unsigned short* wl = wm + wsplit;
        int* counter = (int*)((char*)d_ws + 3 * wsplit * sizeof(unsigned short));
        int* list    = counter + 1;
        wconvert_kernel<<<(int)(wsplit / 256), 256, 0, stream>>>(W, wh, wm, wl, counter);
        router_mfma_kernel<<<N_TOK / BM, 256, 0, stream>>>(x, wh, wm, wl, b, logits);
        topk_kernel<1><<<N_TOK / 16, 256, 0, stream>>>(logits, wout, iout, counter, list);
        fixup_kernel<<<128, 256, 0, stream>>>(x, W, b, wout, iout, counter, list);
    } else {
        router_logits_f32<<<N_TOK / 32, 256, 0, stream>>>(x, W, b, logits);
        topk_kernel<0><<<N_TOK / 16, 256, 0, stream>>>(logits, wout, iout, nullptr, nullptr);
    }
    mask_kernel<<<(N_EXP * 2 * N_TOK) / 256, 256, 0, stream>>>(iout, mask);
}